// Round 9
// baseline (3552.406 us; speedup 1.0000x reference)
//
#include <hip/hip_runtime.h>
#include <stdint.h>

// LSTM scan, B=64, T=16384, H=32, I=O=1, fp32 in/out.
// ONE WAVE PER BATCH (64 blocks x 64 threads). Issue-bound: VALUBusy ~5.2%
// vs the 6.25% 64-wave ceiling => active SIMD issues ~83% of cycles; wall
// time ~ dynamic VALU instrs/step (~480 cyc/step at R11).
//
// Round-13: resubmit of round-12 (compile error only: cvt_pkrtz returns an
// __fp16-based vector, fdot2 wants _Float16-based; bridge with bit_cast).
// Halve the h-broadcast with f16 pair packing + v_dot2_f32_f16:
//   R11 matvec/step: 32 v_readlane + ~32 v_mov + 32 v_pk_fma  (~96 instrs)
//   R13:             1 dpp + 1 cvt_pkrtz + 16 rl + ~16 mov + 32 fdot2 (~66)
//   plus the serial horizontal .x+.y reduce disappears (scalar accs).
// Pair forming: hx = mov_dpp quad_perm(1,0,3,2) (VALU xor-1 neighbor, no DS
// pipe; builtin so the compiler inserts DPP hazard waits), then
// hpk = cvt_pkrtz(h, hx): even B-lane 32+2m holds (h_2m, h_2m+1) and ONE
// readlane feeds both halves of a dot2.
// Precision scope: f16 ONLY on the recurrent matvec operands (W_hh pre-
// scaled weights + h broadcast). h, c, x-path, epilogue linear all f32.
// Fallback (no fdot2): exact R11 path.
//
// Ledger: cross-session noise ~150us (R4's 3223 vs later 3368-3390 for
// near-identical kernels). Failed: R5 4-chain (+instrs), R6 PIN, R7 LDS
// broadcast (serial DS roundtrip), R8 scalar-fmac+waves_per_eu (residency
// neutral), R9/10 SGPR-pair pk_fma (VALU->SGPR->VALU hazard). R11 algebra
// (pre-scaled weights, C-space cell, fused affines) = small real win, kept.
//
// Lane mapping (validated): j = lane&31, half = lane>>5.
//   A-lanes (half=0): gates i (row j)    and g (row 64+j)
//   B-lanes (half=1): gates f (row 32+j) and o (row 96+j)
// B-lanes hold the real C,h. A-lanes compute bounded garbage: q_A = KT*f*o
// in (KT,0), a1 in (0,1) -> C_A stays negative/finite; h_A in (-1,1).
// Cross-half exchange: permlane32_swap builtin + XOR identity (exact).

#define HID 32
#define CHUNK 32

typedef float f2 __attribute__((ext_vector_type(2)));
typedef float f4 __attribute__((ext_vector_type(4)));
typedef _Float16 h2 __attribute__((ext_vector_type(2)));   // fdot2 operand type
typedef __fp16   g2 __attribute__((ext_vector_type(2)));   // cvt_pkrtz result type
typedef unsigned int u32x2 __attribute__((ext_vector_type(2)));

#if defined(__has_builtin)
#if __has_builtin(__builtin_amdgcn_permlane32_swap)
#define HAVE_PLSWAP 1
#endif
#if __has_builtin(__builtin_amdgcn_fdot2) && \
    __has_builtin(__builtin_amdgcn_mov_dpp) && \
    __has_builtin(__builtin_amdgcn_cvt_pkrtz)
#define HAVE_DOT2 1
#endif
#endif

__device__ __forceinline__ float rl(float v, int lane) {
    return __int_as_float(__builtin_amdgcn_readlane(__float_as_int(v), lane));
}

#ifdef HAVE_DOT2
__device__ __forceinline__ h2 pk16(float a, float b) {
    const g2 t = __builtin_amdgcn_cvt_pkrtz(a, b);
    return __builtin_bit_cast(h2, t);
}
#endif

// Exchange p across wave halves: every lane gets the other half's p
// (for its own j). VALU-only on gfx950; DS-pipe fallback otherwise.
__device__ __forceinline__ float cross_half(float p) {
#ifdef HAVE_PLSWAP
    const unsigned pu = __float_as_uint(p);
    u32x2 r = __builtin_amdgcn_permlane32_swap(pu, pu, false, false);
    return __uint_as_float(r[0] ^ r[1] ^ pu);   // exact, orientation-independent
#else
    return __shfl_xor(p, 32, 64);
#endif
}

__global__ __launch_bounds__(64, 1)
void lstm_wave_scan(const float* __restrict__ x,
                    const float* __restrict__ W_ih,
                    const float* __restrict__ W_hh,
                    const float* __restrict__ b_ih,
                    const float* __restrict__ b_hh,
                    const float* __restrict__ W_lin,
                    const float* __restrict__ b_lin,
                    float* __restrict__ out,
                    int T) {
    __shared__ float h_hist[CHUNK][65];   // row stride 65: epilogue conflict-free

    const int lane = threadIdx.x;
    const int j    = lane & 31;
    const int half = lane >> 5;
    const int b    = blockIdx.x;

    const int row1 = j + (half << 5);         // A: i-row j     B: f-row 32+j
    const int row2 = 64 + j + (half << 5);    // A: g-row 64+j  B: o-row 96+j

    const float K1 = -1.44269504088896340736f;   // -log2(e): sigmoid arg scale
    const float KT = -2.88539008177792681472f;   // -2*log2(e): tanh-as-sigmoid
    const float K2 = half ? K1 : KT;             // gate2: B=o (sig), A=g (tanh)
    const float cu = half ? KT : 2.0f * KT;      // p = fma(r2, cu*a1, cv*a1)
    const float cv = half ? 0.0f : -KT;          //   (p lives in C-space)

#ifdef HAVE_DOT2
    // Pre-scaled weights, packed f16 pairs: wf[m] = (K*W[row][2m], K*W[row][2m+1]).
    // |K2*w| <= 2.89*0.177 ~ 0.52 -> comfortably in f16 range.
    h2 wf1[16], wf2[16];
    {
        const f4* R1 = (const f4*)(W_hh + row1 * HID);
        const f4* R2 = (const f4*)(W_hh + row2 * HID);
#pragma unroll
        for (int m = 0; m < 8; ++m) {
            f4 v1 = R1[m];
            wf1[2*m]   = pk16(v1.x * K1, v1.y * K1);
            wf1[2*m+1] = pk16(v1.z * K1, v1.w * K1);
            f4 v2 = R2[m];
            wf2[2*m]   = pk16(v2.x * K2, v2.y * K2);
            wf2[2*m+1] = pk16(v2.z * K2, v2.w * K2);
        }
    }
#else
    f2 w1[16], w2[16];
    {
        const f4* R1 = (const f4*)(W_hh + row1 * HID);
        const f4* R2 = (const f4*)(W_hh + row2 * HID);
#pragma unroll
        for (int m = 0; m < 8; ++m) {
            f4 v1 = R1[m];
            w1[2*m]   = f2{v1.x * K1, v1.y * K1};
            w1[2*m+1] = f2{v1.z * K1, v1.w * K1};
            f4 v2 = R2[m];
            w2[2*m]   = f2{v2.x * K2, v2.y * K2};
            w2[2*m+1] = f2{v2.z * K2, v2.w * K2};
        }
    }
#endif
    const float wih1 = W_ih[row1] * K1;
    const float bb1  = (b_ih[row1] + b_hh[row1]) * K1;
    const float wih2 = W_ih[row2] * K2;
    const float bb2  = (b_ih[row2] + b_hh[row2]) * K2;
    const float blin = b_lin[0];

    float C = 0.0f;     // B-lanes: KT * cell state  (A-lanes: bounded garbage)
    float h = 0.0f;     // B-lanes: hidden state h_{t-1}
#ifdef HAVE_DOT2
    int hpk = 0;        // even B-lanes: f16x2 (h_j, h_{j+1}); h_{-1} = 0
#endif

    const float* xb = x   + (size_t)b * T;
    float*       ob = out + (size_t)b * T;

    float xv = xb[j];

    for (int t0 = 0; t0 < T; t0 += CHUNK) {
        int t0n = t0 + CHUNK; if (t0n >= T) t0n = 0;
        float xv_next = xb[t0n + j];

#pragma unroll 8
        for (int tt = 0; tt < CHUNK; ++tt) {
            const float sx = rl(xv, tt);  // wave-uniform x_t

#ifdef HAVE_DOT2
            // Matvec: one readlane per PAIR (even B-lane 32+2m holds the
            // packed (h_2m, h_2m+1)); two fdot2 per pair; scalar f32 accs
            // (no horizontal reduce). Two interleaved chains, 4-cyc spacing
            // = dot2 latency -> no bubbles.
            float a1acc = __builtin_fmaf(sx, wih1, bb1);
            float a2acc = __builtin_fmaf(sx, wih2, bb2);
#pragma unroll
            for (int m = 0; m < 16; ++m) {
                const int hm = __builtin_amdgcn_readlane(hpk, 32 + 2*m);
                const h2 hv = __builtin_bit_cast(h2, hm);
                a1acc = __builtin_amdgcn_fdot2(wf1[m], hv, a1acc, false);
                a2acc = __builtin_amdgcn_fdot2(wf2[m], hv, a2acc, false);
            }
            const float m1 = a1acc;     // A: K1*i-pre   B: K1*f-pre
            const float m2 = a2acc;     // A: KT*g-pre   B: K1*o-pre
#else
            f2 acc1 = f2{ __builtin_fmaf(sx, wih1, bb1), 0.0f };
            f2 acc2 = f2{ __builtin_fmaf(sx, wih2, bb2), 0.0f };
#pragma unroll
            for (int m = 0; m < 16; ++m) {
                f2 hm = f2{ rl(h, 32 + 2*m), rl(h, 32 + 2*m + 1) };
                acc1 = __builtin_elementwise_fma(w1[m], hm, acc1);
                acc2 = __builtin_elementwise_fma(w2[m], hm, acc2);
            }
            const float m1 = acc1.x + acc1.y;
            const float m2 = acc2.x + acc2.y;
#endif

            // bare exp2 -> add -> rcp (scales pre-folded into m1/m2)
            const float a1 = __builtin_amdgcn_rcpf(1.0f + __builtin_amdgcn_exp2f(m1));
            const float r2 = __builtin_amdgcn_rcpf(1.0f + __builtin_amdgcn_exp2f(m2));

            const float uu = cu * a1;       // off the r2 chain (parallel)
            const float vv = cv * a1;
            const float o2 = r2 + r2;       // off the C chain
            const float on = -r2;

            const float p = __builtin_fmaf(r2, uu, vv);
                                            // A: KT*i*tanh(g)   B: KT*f*o
            const float q = cross_half(p);  // A: KT*f*o         B: KT*i*tanh(g)

            C = __builtin_fmaf(a1, C, q);   // B: KT*(f*c + i*g~)
            const float sg = __builtin_amdgcn_rcpf(1.0f + __builtin_amdgcn_exp2f(C));
                                            // B: sigmoid(2c)
            h = __builtin_fmaf(sg, o2, on); // B: o*(2*sig(2c)-1) = o*tanh(c)

#ifdef HAVE_DOT2
            // Pack (h_j, h_{j^1}) for next step's broadcast: xor-1 neighbor
            // via DPP quad_perm(1,0,3,2) (VALU, compiler handles hazards),
            // then cvt_pkrtz. Valid pairs land in even lanes.
            {
                const int hxi = __builtin_amdgcn_mov_dpp(
                    __float_as_int(h), 0xB1, 0xF, 0xF, true);
                const h2 hp = pk16(h, __int_as_float(hxi));
                hpk = __builtin_bit_cast(int, hp);
            }
#endif
            h_hist[tt][lane] = h;           // cols 32..63 hold the real h (f32)
        }

        // ---- epilogue: out[b][t0+t'] = x + W_lin . h_t' + b_lin, t' = j
        // (full f32: h_hist holds unquantized h)
        {
            float facc = 0.0f;
#pragma unroll
            for (int k = 0; k < 32; ++k)
                facc = __builtin_fmaf(W_lin[k], h_hist[j][32 + k], facc);
            if (half == 0)
                ob[t0 + j] = xv + facc + blin;
        }

        xv = xv_next;
    }
}

extern "C" void kernel_launch(void* const* d_in, const int* in_sizes, int n_in,
                              void* d_out, int out_size, void* d_ws, size_t ws_size,
                              hipStream_t stream) {
    const float* x     = (const float*)d_in[0];
    const float* W_ih  = (const float*)d_in[1];
    const float* W_hh  = (const float*)d_in[2];
    const float* b_ih  = (const float*)d_in[3];
    const float* b_hh  = (const float*)d_in[4];
    const float* W_lin = (const float*)d_in[5];
    const float* b_lin = (const float*)d_in[6];
    float* out = (float*)d_out;

    const int B = 64;
    const int T = in_sizes[0] / B;   // 16384

    dim3 grid(B);
    dim3 block(64);
    lstm_wave_scan<<<grid, block, 0, stream>>>(x, W_ih, W_hh, b_ih, b_hh,
                                               W_lin, b_lin, out, T);
}